// Round 10
// baseline (210.446 us; speedup 1.0000x reference)
//
#include <hip/hip_runtime.h>

#define T_TRIG 48
#define S_SPAN 128
#define NN (T_TRIG * S_SPAN)      // 6144 nodes
#define D 128                     // feature dim
#define GRID 192                  // (r,h) blocks; 192 <= 256 CUs -> co-resident
#define BLK 1024

typedef __attribute__((ext_vector_type(8))) short sh8;
typedef __attribute__((ext_vector_type(4))) float f32x4;
typedef __attribute__((ext_vector_type(4))) unsigned short us4;

__device__ inline unsigned short f2bf(float v) {
    unsigned u = __float_as_uint(v);
    unsigned r = u + 0x7FFFu + ((u >> 16) & 1u);   // RTNE
    return (unsigned short)(r >> 16);
}
__device__ inline float bf2f(unsigned short b) {
    return __uint_as_float(((unsigned)b) << 16);
}

struct Params {
    const float *pe, *W1, *as1, *ad1, *b1, *W2, *as2, *ad2, *b2;
    float* out;
    unsigned int* bar;
    unsigned short *x2h, *x2l;
    float *H, *numr, *asrc, *adst, *den;
};

// ---- grid barrier (round-8/9-proven semantics) ----------------------------
__device__ inline void gridbar(unsigned int* cnt) {
    asm volatile("s_waitcnt vmcnt(0)" ::: "memory");
    __syncthreads();
    if (threadIdx.x == 0) {
        asm volatile("buffer_wbl2 sc1\n\ts_waitcnt vmcnt(0)" ::: "memory");
        atomicAdd(cnt, 1u);
        while (__hip_atomic_load(cnt, __ATOMIC_RELAXED, __HIP_MEMORY_SCOPE_AGENT) < GRID)
            __builtin_amdgcn_s_sleep(8);
        asm volatile("buffer_inv sc1\n\ts_waitcnt vmcnt(0)" ::: "memory");
    }
    __syncthreads();
    __builtin_amdgcn_sched_barrier(0);
}

// ---------------------------------------------------------------------------
// GR phase: block (r,h) = 192 blocks x 16 waves. GEMM for grid-row r
// (128 nodes) x head h (32 feats): wave w -> mtile w>>1, ntile w&1 (16x16).
// H slice kept in LDS; then block-local row aggregation (8 thr/dest).
// ---------------------------------------------------------------------------
template<int LAYER>
__device__ void gr_phase(const Params& p, float* sm, int b, int t)
{
    const int r = b >> 2, h = b & 3;
    const int w = t >> 6, l = t & 63;
    const int c = l & 15, kg = l >> 4;
    const int mt = w >> 1, nt = w & 1;
    const int row0 = r * S_SPAN + mt * 16;
    const int col0 = h * 32 + nt * 16;

    float (*sh_h)[36] = (float(*)[36])sm;          // 128 x 36 (padded)
    float* sh_ps = sm + 128 * 36;                  // [2][128] asrc partials
    float* sh_pd = sh_ps + 256;                    // [2][128] adst partials
    float* sh_as = sh_pd + 256;                    // 128 combined
    float* sh_ad = sh_as + 128;                    // 128 combined

    const float* W     = (LAYER == 1) ? p.W1  : p.W2;
    const float* att_s = (LAYER == 1) ? p.as1 : p.as2;
    const float* att_d = (LAYER == 1) ? p.ad1 : p.ad2;

    f32x4 acc = {0,0,0,0};
    #pragma unroll
    for (int kc = 0; kc < 4; ++kc) {
        sh8 ah, al;
        if (LAYER == 1) {
            const float* xp = p.pe + (size_t)(row0 + c) * D + kc * 32 + kg * 8;
            float4 x0 = *(const float4*)xp;
            float4 x1 = *(const float4*)(xp + 4);
            float xs[8] = {x0.x, x0.y, x0.z, x0.w, x1.x, x1.y, x1.z, x1.w};
            #pragma unroll
            for (int i = 0; i < 8; ++i) {
                unsigned short hh = f2bf(xs[i]);
                ah[i] = (short)hh;
                al[i] = (short)f2bf(xs[i] - bf2f(hh));
            }
        } else {
            const int xi = (row0 + c) * 16 + kc * 4 + kg;
            ah = ((const sh8*)p.x2h)[xi];
            al = ((const sh8*)p.x2l)[xi];
        }
        const int kb = kc * 32 + kg * 8;
        sh8 bh, bl;
        #pragma unroll
        for (int i = 0; i < 8; ++i) {
            float v = W[(size_t)(kb + i) * D + col0 + c];
            unsigned short h0 = f2bf(v);
            bh[i] = (short)h0;
            bl[i] = (short)f2bf(v - bf2f(h0));
        }
        acc = __builtin_amdgcn_mfma_f32_16x16x32_bf16(ah, bh, acc, 0, 0, 0);
        acc = __builtin_amdgcn_mfma_f32_16x16x32_bf16(al, bh, acc, 0, 0, 0);
        acc = __builtin_amdgcn_mfma_f32_16x16x32_bf16(ah, bl, acc, 0, 0, 0);
    }

    // H slice -> LDS and global
    #pragma unroll
    for (int i = 0; i < 4; ++i) {
        const int rl = mt * 16 + kg * 4 + i;
        sh_h[rl][nt * 16 + c] = acc[i];
        p.H[(size_t)(row0 + kg * 4 + i) * D + col0 + c] = acc[i];
    }

    // attention partials (this wave's 16 feats)
    const float asv = att_s[col0 + c];
    const float adv = att_d[col0 + c];
    #pragma unroll
    for (int i = 0; i < 4; ++i) {
        float ps = acc[i] * asv;
        float pd = acc[i] * adv;
        ps += __shfl_xor(ps, 1); pd += __shfl_xor(pd, 1);
        ps += __shfl_xor(ps, 2); pd += __shfl_xor(pd, 2);
        ps += __shfl_xor(ps, 4); pd += __shfl_xor(pd, 4);
        ps += __shfl_xor(ps, 8); pd += __shfl_xor(pd, 8);
        if (c == 0) {
            const int rl = mt * 16 + kg * 4 + i;
            sh_ps[nt * 128 + rl] = ps;
            sh_pd[nt * 128 + rl] = pd;
        }
    }
    __syncthreads();
    if (t < 128) {
        float ps = sh_ps[t] + sh_ps[128 + t];
        float pd = sh_pd[t] + sh_pd[128 + t];
        sh_as[t] = ps;
        sh_ad[t] = pd;
        p.asrc[(r * S_SPAN + t) * 4 + h] = ps;
        p.adst[(r * S_SPAN + t) * 4 + h] = pd;
    }
    __syncthreads();

    // block-local row aggregation: thread = (dst d, feat-quad fg)
    const int d = t >> 3, fg = t & 7;
    const float ad = sh_ad[d];
    f32x4 n0 = {0,0,0,0};
    float dn = 0.f;
    #pragma unroll 4
    for (int cp = 0; cp < S_SPAN; ++cp) {
        float e = sh_as[cp] + ad;
        e = fmaxf(e, 0.2f * e);
        float wgt = __expf(e);
        dn += wgt;
        f32x4 hv = *(f32x4*)&sh_h[cp][fg * 4];
        #pragma unroll
        for (int q = 0; q < 4; ++q) n0[q] = fmaf(wgt, hv[q], n0[q]);
    }
    const int node = r * S_SPAN + d;
    *(f32x4*)&p.numr[(size_t)node * D + h * 32 + fg * 4] = n0;
    if (fg == 0) p.den[node * 4 + h] = dn;
}

// ---------------------------------------------------------------------------
// COL phase: block c (b < 128 active), 1024 threads. Stages H[:,c,:]
// (48x128), adds col-part (excluding own row), merges with row numerators,
// bias + ELU. Thread = (row-group tg 0..31 -> rows {tg, tg+32}, feat-quad).
// ---------------------------------------------------------------------------
template<int LAYER>
__device__ void col_phase(const Params& p, float* sm, int b, int t)
{
    if (b >= S_SPAN) return;
    const int c = b;
    float (*sh_hc)[132] = (float(*)[132])sm;                 // 48 x 132 (pad)
    float (*sh_asc)[T_TRIG] = (float(*)[T_TRIG])(sm + 48 * 132);

    #pragma unroll
    for (int it = 0; it < 2; ++it) {
        int chunk = t + it * BLK;                 // 1536 float4 chunks
        if (chunk < 1536) {
            int tt = chunk >> 5, fc = chunk & 31;
            *(float4*)&sh_hc[tt][fc * 4] =
                *(const float4*)&p.H[(size_t)(tt * S_SPAN + c) * D + fc * 4];
        }
    }
    if (t < 4 * T_TRIG) {
        int hh = t / T_TRIG, tt = t - hh * T_TRIG;
        sh_asc[hh][tt] = p.asrc[(tt * S_SPAN + c) * 4 + hh];
    }
    __syncthreads();

    const int f4g = t & 31, tg = t >> 5, head = f4g >> 3;    // tg 0..31
    const float* bias = (LAYER == 1) ? p.b1 : p.b2;
    const int nrows = (tg < 16) ? 2 : 1;                      // rows tg, tg+32

    f32x4 num[2] = {{0,0,0,0},{0,0,0,0}};
    float dn[2] = {0.f, 0.f};
    float ad[2] = {0.f, 0.f};
    for (int dd = 0; dd < nrows; ++dd)
        ad[dd] = p.adst[((tg + dd * 32) * S_SPAN + c) * 4 + head];

    for (int tp = 0; tp < T_TRIG; ++tp) {
        float a = sh_asc[head][tp];
        f32x4 hv = *(f32x4*)&sh_hc[tp][f4g * 4];
        for (int dd = 0; dd < nrows; ++dd) {
            float e = a + ad[dd];
            e = fmaxf(e, 0.2f * e);
            float wgt = __expf(e);
            wgt = (tp == tg + dd * 32) ? 0.f : wgt;   // exclude own row
            dn[dd] += wgt;
            #pragma unroll
            for (int q = 0; q < 4; ++q) num[dd][q] = fmaf(wgt, hv[q], num[dd][q]);
        }
    }

    const float4 b4 = *(const float4*)&bias[f4g * 4];
    const float bb[4] = {b4.x, b4.y, b4.z, b4.w};
    for (int dd = 0; dd < nrows; ++dd) {
        const int n = (tg + dd * 32) * S_SPAN + c;
        f32x4 nr = *(const f32x4*)&p.numr[(size_t)n * D + f4g * 4];
        float inv = 1.f / (p.den[n * 4 + head] + dn[dd]);
        float o[4];
        #pragma unroll
        for (int q = 0; q < 4; ++q) {
            o[q] = (nr[q] + num[dd][q]) * inv + bb[q];
            o[q] = o[q] > 0.f ? o[q] : (__expf(o[q]) - 1.f);
        }
        if (LAYER == 1) {
            us4 hv4, lv4;
            #pragma unroll
            for (int q = 0; q < 4; ++q) {
                unsigned short hq = f2bf(o[q]);
                hv4[q] = hq;
                lv4[q] = f2bf(o[q] - bf2f(hq));
            }
            *(us4*)&p.x2h[(size_t)n * D + f4g * 4] = hv4;
            *(us4*)&p.x2l[(size_t)n * D + f4g * 4] = lv4;
        } else {
            float4 o4 = {o[0], o[1], o[2], o[3]};
            *(float4*)&p.out[(size_t)n * D + f4g * 4] = o4;
        }
    }
}

// ---- the single fused kernel: 4 phases, 3 grid barriers --------------------
__global__ __launch_bounds__(BLK, 4) void fused_gat_kernel(Params p)
{
    __shared__ float sm[48 * 132 + 4 * T_TRIG];   // 26,112 B (col-phase max)
    const int b = blockIdx.x, t = threadIdx.x;

    gr_phase<1>(p, sm, b, t);
    gridbar(p.bar + 0);
    col_phase<1>(p, sm, b, t);
    gridbar(p.bar + 32);
    gr_phase<2>(p, sm, b, t);
    gridbar(p.bar + 64);
    col_phase<2>(p, sm, b, t);
}

// ---------------------------------------------------------------------------
extern "C" void kernel_launch(void* const* d_in, const int* in_sizes, int n_in,
                              void* d_out, int out_size, void* d_ws, size_t ws_size,
                              hipStream_t stream)
{
    Params p;
    p.pe  = (const float*)d_in[0];
    p.W1  = (const float*)d_in[1];
    p.as1 = (const float*)d_in[2];
    p.ad1 = (const float*)d_in[3];
    p.b1  = (const float*)d_in[4];
    p.W2  = (const float*)d_in[5];
    p.as2 = (const float*)d_in[6];
    p.ad2 = (const float*)d_in[7];
    p.b2  = (const float*)d_in[8];
    p.out = (float*)d_out;

    char* ws = (char*)d_ws;
    size_t off = 0;
    auto alloc = [&](size_t bytes) { char* r = ws + off; off += (bytes + 255) & ~255ull; return r; };
    p.bar  = (unsigned int*)alloc(512);
    p.x2h  = (unsigned short*)alloc((size_t)NN * D * 2);
    p.x2l  = (unsigned short*)alloc((size_t)NN * D * 2);
    p.H    = (float*)alloc((size_t)NN * D * 4);
    p.numr = (float*)alloc((size_t)NN * D * 4);
    p.asrc = (float*)alloc((size_t)NN * 4 * 4);
    p.adst = (float*)alloc((size_t)NN * 4 * 4);
    p.den  = (float*)alloc((size_t)NN * 4 * 4);

    hipMemsetAsync(p.bar, 0, 512, stream);
    fused_gat_kernel<<<dim3(GRID), dim3(BLK), 0, stream>>>(p);
}

// Round 11
// 79.273 us; speedup vs baseline: 2.6547x; 2.6547x over previous
//
#include <hip/hip_runtime.h>

#define T_TRIG 48
#define S_SPAN 128
#define NN (T_TRIG * S_SPAN)      // 6144 nodes
#define D 128                     // feature dim
#define GRID 192                  // (r,h) blocks; <= 256 CUs -> co-resident
#define BLK 512

typedef __attribute__((ext_vector_type(8))) short sh8;
typedef __attribute__((ext_vector_type(4))) float f32x4;
typedef __attribute__((ext_vector_type(4))) unsigned short us4;

__device__ inline unsigned short f2bf(float v) {
    unsigned u = __float_as_uint(v);
    unsigned r = u + 0x7FFFu + ((u >> 16) & 1u);   // RTNE
    return (unsigned short)(r >> 16);
}
__device__ inline float bf2f(unsigned short b) {
    return __uint_as_float(((unsigned)b) << 16);
}

struct Params {
    const float *pe, *W1, *as1, *ad1, *b1, *W2, *as2, *ad2, *b2;
    float* out;
    unsigned int* bar;
    unsigned short *x2h, *x2l;
    float *H, *numr, *asrc, *adst, *den;
};

// ---- grid barrier with 8-way tree arrival ---------------------------------
// Layout per phase (512 uints = 2 KB): group counters at g*32 (128 B apart),
// root at 8*32. Groups of 24 blocks arrive on 8 separate lines in parallel;
// last arriver per group bumps root. Release/acquire via per-block wbl2/inv
// (round-8/9-proven). Serial RMW chain per barrier: ~24 + 8 instead of 192.
__device__ inline void gridbar(unsigned int* bars, int phase) {
    asm volatile("s_waitcnt vmcnt(0)" ::: "memory");
    __syncthreads();
    if (threadIdx.x == 0) {
        asm volatile("buffer_wbl2 sc1\n\ts_waitcnt vmcnt(0)" ::: "memory");
        unsigned int* base = bars + phase * 512;
        unsigned int* gc   = base + (blockIdx.x & 7) * 32;
        unsigned int* root = base + 8 * 32;
        unsigned int prev = atomicAdd(gc, 1u);
        if (prev == (GRID / 8) - 1) atomicAdd(root, 1u);
        while (__hip_atomic_load(root, __ATOMIC_RELAXED, __HIP_MEMORY_SCOPE_AGENT) < 8u)
            __builtin_amdgcn_s_sleep(2);
        asm volatile("buffer_inv sc1\n\ts_waitcnt vmcnt(0)" ::: "memory");
    }
    __syncthreads();
    __builtin_amdgcn_sched_barrier(0);
}

// ---------------------------------------------------------------------------
// GR phase: block (r,h). GEMM for grid-row r (128 nodes) x head h (32 feats),
// split-bf16 MFMA, H slice kept in LDS; then block-local row aggregation.
// ---------------------------------------------------------------------------
template<int LAYER>
__device__ void gr_phase(const Params& p, float* sm, int b, int t)
{
    const int r = b >> 2, h = b & 3;
    const int w = t >> 6, l = t & 63;
    const int c = l & 15, kg = l >> 4;
    const int row0 = r * S_SPAN + w * 16;   // global node base for this wave
    const int col0 = h * 32;

    float (*sh_h)[36] = (float(*)[36])sm;          // 128 x 36 (padded)
    float* sh_as = sm + 128 * 36;
    float* sh_ad = sh_as + 128;

    const float* W     = (LAYER == 1) ? p.W1  : p.W2;
    const float* att_s = (LAYER == 1) ? p.as1 : p.as2;
    const float* att_d = (LAYER == 1) ? p.ad1 : p.ad2;

    f32x4 a0 = {0,0,0,0}, a1 = {0,0,0,0};
    #pragma unroll
    for (int kc = 0; kc < 4; ++kc) {
        sh8 ah, al;
        if (LAYER == 1) {
            const float* xp = p.pe + (size_t)(row0 + c) * D + kc * 32 + kg * 8;
            float4 x0 = *(const float4*)xp;
            float4 x1 = *(const float4*)(xp + 4);
            float xs[8] = {x0.x, x0.y, x0.z, x0.w, x1.x, x1.y, x1.z, x1.w};
            #pragma unroll
            for (int i = 0; i < 8; ++i) {
                unsigned short hh = f2bf(xs[i]);
                ah[i] = (short)hh;
                al[i] = (short)f2bf(xs[i] - bf2f(hh));
            }
        } else {
            const int xi = (row0 + c) * 16 + kc * 4 + kg;
            ah = ((const sh8*)p.x2h)[xi];
            al = ((const sh8*)p.x2l)[xi];
        }
        const int kb = kc * 32 + kg * 8;
        sh8 b0h, b0l, b1h, b1l;
        #pragma unroll
        for (int i = 0; i < 8; ++i) {
            float v0 = W[(size_t)(kb + i) * D + col0 + c];
            float v1 = W[(size_t)(kb + i) * D + col0 + 16 + c];
            unsigned short h0 = f2bf(v0);
            b0h[i] = (short)h0; b0l[i] = (short)f2bf(v0 - bf2f(h0));
            unsigned short h1 = f2bf(v1);
            b1h[i] = (short)h1; b1l[i] = (short)f2bf(v1 - bf2f(h1));
        }
        a0 = __builtin_amdgcn_mfma_f32_16x16x32_bf16(ah, b0h, a0, 0, 0, 0);
        a0 = __builtin_amdgcn_mfma_f32_16x16x32_bf16(al, b0h, a0, 0, 0, 0);
        a0 = __builtin_amdgcn_mfma_f32_16x16x32_bf16(ah, b0l, a0, 0, 0, 0);
        a1 = __builtin_amdgcn_mfma_f32_16x16x32_bf16(ah, b1h, a1, 0, 0, 0);
        a1 = __builtin_amdgcn_mfma_f32_16x16x32_bf16(al, b1h, a1, 0, 0, 0);
        a1 = __builtin_amdgcn_mfma_f32_16x16x32_bf16(ah, b1l, a1, 0, 0, 0);
    }

    // H slice -> LDS (row-agg input) and global (col-phase input)
    #pragma unroll
    for (int i = 0; i < 4; ++i) {
        const int rl = w * 16 + kg * 4 + i;       // 0..127 local node
        sh_h[rl][c]      = a0[i];
        sh_h[rl][16 + c] = a1[i];
        p.H[(size_t)(row0 + kg * 4 + i) * D + col0 + c]      = a0[i];
        p.H[(size_t)(row0 + kg * 4 + i) * D + col0 + 16 + c] = a1[i];
    }

    // attention scalars for head h
    const float as0 = att_s[col0 + c],  as1v = att_s[col0 + 16 + c];
    const float ad0 = att_d[col0 + c],  ad1v = att_d[col0 + 16 + c];
    #pragma unroll
    for (int i = 0; i < 4; ++i) {
        float ps = a0[i] * as0 + a1[i] * as1v;
        float pd = a0[i] * ad0 + a1[i] * ad1v;
        ps += __shfl_xor(ps, 1); pd += __shfl_xor(pd, 1);
        ps += __shfl_xor(ps, 2); pd += __shfl_xor(pd, 2);
        ps += __shfl_xor(ps, 4); pd += __shfl_xor(pd, 4);
        ps += __shfl_xor(ps, 8); pd += __shfl_xor(pd, 8);
        if (c == 0) {
            const int rl = w * 16 + kg * 4 + i;
            sh_as[rl] = ps;
            sh_ad[rl] = pd;
            p.asrc[(row0 + kg * 4 + i) * 4 + h] = ps;
            p.adst[(row0 + kg * 4 + i) * 4 + h] = pd;
        }
    }
    __syncthreads();

    // block-local row aggregation: thread = (dst d, feat-group fg)
    const int d = t >> 2, fg = t & 3;
    const float ad = sh_ad[d];
    f32x4 n0 = {0,0,0,0}, n1 = {0,0,0,0};
    float dn = 0.f;
    #pragma unroll 4
    for (int cp = 0; cp < S_SPAN; ++cp) {
        float e = sh_as[cp] + ad;
        e = fmaxf(e, 0.2f * e);
        float wgt = __expf(e);
        dn += wgt;
        f32x4 h0 = *(f32x4*)&sh_h[cp][fg * 8];
        f32x4 h1 = *(f32x4*)&sh_h[cp][fg * 8 + 4];
        #pragma unroll
        for (int q = 0; q < 4; ++q) {
            n0[q] = fmaf(wgt, h0[q], n0[q]);
            n1[q] = fmaf(wgt, h1[q], n1[q]);
        }
    }
    const int node = r * S_SPAN + d;
    *(f32x4*)&p.numr[(size_t)node * D + col0 + fg * 8]     = n0;
    *(f32x4*)&p.numr[(size_t)node * D + col0 + fg * 8 + 4] = n1;
    if (fg == 0) p.den[node * 4 + h] = dn;
}

// ---------------------------------------------------------------------------
// COL phase: block c (only b < 128 active). Stages H[:,c,:] (48x128), adds
// col-part (excluding own row), merges with row numerators, bias + ELU.
// ---------------------------------------------------------------------------
template<int LAYER>
__device__ void col_phase(const Params& p, float* sm, int b, int t)
{
    if (b >= S_SPAN) return;
    const int c = b;
    float (*sh_hc)[132] = (float(*)[132])sm;                 // 48 x 132 (pad)
    float (*sh_asc)[T_TRIG] = (float(*)[T_TRIG])(sm + 48 * 132);

    #pragma unroll
    for (int it = 0; it < 3; ++it) {
        int chunk = t + it * BLK;                 // 1536 float4 chunks
        int tt = chunk >> 5, fc = chunk & 31;
        *(float4*)&sh_hc[tt][fc * 4] =
            *(const float4*)&p.H[(size_t)(tt * S_SPAN + c) * D + fc * 4];
    }
    if (t < 4 * T_TRIG) {
        int hh = t / T_TRIG, tt = t - hh * T_TRIG;
        sh_asc[hh][tt] = p.asrc[(tt * S_SPAN + c) * 4 + hh];
    }
    __syncthreads();

    const int f4g = t & 31, tg = t >> 5, head = f4g >> 3;    // tg 0..15, 3 dsts
    const float* bias = (LAYER == 1) ? p.b1 : p.b2;

    f32x4 num[3] = {{0,0,0,0},{0,0,0,0},{0,0,0,0}};
    float dn[3] = {0.f, 0.f, 0.f};
    float ad[3];
    #pragma unroll
    for (int dd = 0; dd < 3; ++dd)
        ad[dd] = p.adst[((tg * 3 + dd) * S_SPAN + c) * 4 + head];

    for (int tp = 0; tp < T_TRIG; ++tp) {
        float a = sh_asc[head][tp];
        f32x4 hv = *(f32x4*)&sh_hc[tp][f4g * 4];
        #pragma unroll
        for (int dd = 0; dd < 3; ++dd) {
            float e = a + ad[dd];
            e = fmaxf(e, 0.2f * e);
            float wgt = __expf(e);
            wgt = (tp == tg * 3 + dd) ? 0.f : wgt;   // exclude own row
            dn[dd] += wgt;
            #pragma unroll
            for (int q = 0; q < 4; ++q) num[dd][q] = fmaf(wgt, hv[q], num[dd][q]);
        }
    }

    const float4 b4 = *(const float4*)&bias[f4g * 4];
    const float bb[4] = {b4.x, b4.y, b4.z, b4.w};
    #pragma unroll
    for (int dd = 0; dd < 3; ++dd) {
        const int n = (tg * 3 + dd) * S_SPAN + c;
        f32x4 nr = *(const f32x4*)&p.numr[(size_t)n * D + f4g * 4];
        float inv = 1.f / (p.den[n * 4 + head] + dn[dd]);
        float o[4];
        #pragma unroll
        for (int q = 0; q < 4; ++q) {
            o[q] = (nr[q] + num[dd][q]) * inv + bb[q];
            o[q] = o[q] > 0.f ? o[q] : (__expf(o[q]) - 1.f);
        }
        if (LAYER == 1) {
            us4 hv4, lv4;
            #pragma unroll
            for (int q = 0; q < 4; ++q) {
                unsigned short hq = f2bf(o[q]);
                hv4[q] = hq;
                lv4[q] = f2bf(o[q] - bf2f(hq));
            }
            *(us4*)&p.x2h[(size_t)n * D + f4g * 4] = hv4;
            *(us4*)&p.x2l[(size_t)n * D + f4g * 4] = lv4;
        } else {
            float4 o4 = {o[0], o[1], o[2], o[3]};
            *(float4*)&p.out[(size_t)n * D + f4g * 4] = o4;
        }
    }
}

// ---- the single fused kernel: 4 phases, 3 grid barriers --------------------
__global__ __launch_bounds__(BLK, 2) void fused_gat_kernel(Params p)
{
    __shared__ float sm[48 * 132 + 4 * T_TRIG];   // 26.1 KB (col-phase max)
    const int b = blockIdx.x, t = threadIdx.x;

    gr_phase<1>(p, sm, b, t);
    gridbar(p.bar, 0);
    col_phase<1>(p, sm, b, t);
    gridbar(p.bar, 1);
    gr_phase<2>(p, sm, b, t);
    gridbar(p.bar, 2);
    col_phase<2>(p, sm, b, t);
}

// ---------------------------------------------------------------------------
extern "C" void kernel_launch(void* const* d_in, const int* in_sizes, int n_in,
                              void* d_out, int out_size, void* d_ws, size_t ws_size,
                              hipStream_t stream)
{
    Params p;
    p.pe  = (const float*)d_in[0];
    p.W1  = (const float*)d_in[1];
    p.as1 = (const float*)d_in[2];
    p.ad1 = (const float*)d_in[3];
    p.b1  = (const float*)d_in[4];
    p.W2  = (const float*)d_in[5];
    p.as2 = (const float*)d_in[6];
    p.ad2 = (const float*)d_in[7];
    p.b2  = (const float*)d_in[8];
    p.out = (float*)d_out;

    char* ws = (char*)d_ws;
    size_t off = 0;
    auto alloc = [&](size_t bytes) { char* r = ws + off; off += (bytes + 255) & ~255ull; return r; };
    p.bar  = (unsigned int*)alloc(8192);          // 3 phases x 2 KB + slack
    p.x2h  = (unsigned short*)alloc((size_t)NN * D * 2);
    p.x2l  = (unsigned short*)alloc((size_t)NN * D * 2);
    p.H    = (float*)alloc((size_t)NN * D * 4);
    p.numr = (float*)alloc((size_t)NN * D * 4);
    p.asrc = (float*)alloc((size_t)NN * 4 * 4);
    p.adst = (float*)alloc((size_t)NN * 4 * 4);
    p.den  = (float*)alloc((size_t)NN * 4 * 4);

    hipMemsetAsync(p.bar, 0, 8192, stream);
    fused_gat_kernel<<<dim3(GRID), dim3(BLK), 0, stream>>>(p);
}